// Round 16
// baseline (33.905 us; speedup 1.0000x reference)
//
#include <hip/hip_runtime.h>
#include <hip/hip_bf16.h>
#include <math.h>

#define B_ 128
#define IN_ 1024
#define D_ 128
#define H_ 512
#define S_ 256

typedef __attribute__((ext_vector_type(8))) short short8v;
typedef __attribute__((ext_vector_type(8))) unsigned short ushort8v;
typedef __attribute__((ext_vector_type(4))) unsigned short ushort4v;
typedef __attribute__((ext_vector_type(4))) float f32x4;

__device__ __forceinline__ float softplusf(float x) {
  return fmaxf(x, 0.f) + log1pf(expf(-fabsf(x)));
}

__device__ __forceinline__ unsigned short f2bf(float f) {
  unsigned u = __float_as_uint(f);
  unsigned r = (u + 0x7fff + ((u >> 16) & 1)) >> 16;   // RNE
  return (unsigned short)r;
}

// load 8 consecutive fp32 at p, convert to bf16 fragment
__device__ __forceinline__ short8v ld_frag8(const float* __restrict__ p) {
  const float4 v0 = *(const float4*)(p);
  const float4 v1 = *(const float4*)(p + 4);
  short8v s;
  s[0] = (short)f2bf(v0.x); s[1] = (short)f2bf(v0.y);
  s[2] = (short)f2bf(v0.z); s[3] = (short)f2bf(v0.w);
  s[4] = (short)f2bf(v1.x); s[5] = (short)f2bf(v1.y);
  s[6] = (short)f2bf(v1.z); s[7] = (short)f2bf(v1.w);
  return s;
}

// ============ Kpack2: fragment packs only (384 blocks x 256) ============
// [0,64)    : Bp  = W1 w-half fragments (verified)
// [64,128)  : Bz  = W1 z-half fragments (verified pattern)
// [128,256) : BwT = W fragments, col=i k=d (verified, for pxw)
// [256,384) : BdT = W fragments, col=d k=i (NEW, for pwx GEMM)
__global__ __launch_bounds__(256) void Kpack2(
    const float* __restrict__ W, const float* __restrict__ W1,
    unsigned short* __restrict__ Bp, unsigned short* __restrict__ Bz,
    unsigned short* __restrict__ BwT, unsigned short* __restrict__ BdT) {
  const int blk = blockIdx.x;
  const int t = threadIdx.x;

  if (blk < 128) {
    const int zhalf = (blk >= 64);
    const int o = ((blk & 63) * 256 + t) * 4;
    const int frag = o >> 9;
    const int l = (o >> 3) & 63;
    const int j0 = o & 7;
    const int h = (frag >> 2) * 16 + (l & 15);
    const int k0 = (frag & 3) * 32 + ((l >> 4) << 3) + j0;
    const float4 v = *(const float4*)(W1 + (size_t)h * 256 + (zhalf ? 0 : 128) + k0);
    ushort4v u;
    u[0] = f2bf(v.x); u[1] = f2bf(v.y); u[2] = f2bf(v.z); u[3] = f2bf(v.w);
    *(ushort4v*)((zhalf ? Bz : Bp) + o) = u;
  } else if (blk < 256) {
    const int o = ((blk - 128) * 256 + t) * 4;
    const int frag = o >> 9;
    const int l = (o >> 3) & 63;
    const int j0 = o & 7;
    const int i = (frag >> 2) * 16 + (l & 15);
    const int k0 = (frag & 3) * 32 + ((l >> 4) << 3) + j0;
    const float4 v = *(const float4*)(W + (size_t)i * D_ + k0);
    ushort4v u;
    u[0] = f2bf(v.x); u[1] = f2bf(v.y); u[2] = f2bf(v.z); u[3] = f2bf(v.w);
    *(ushort4v*)(BwT + o) = u;
  } else {
    // BdT: frag = dtile*32 + ks; d = dtile*16 + (l&15); k = ks*32 + (l>>4)*8 + j
    const int o = ((blk - 256) * 256 + t) * 4;
    const int frag = o >> 9;            // 0..255
    const int l = (o >> 3) & 63;
    const int j0 = o & 7;
    const int d = (frag >> 5) * 16 + (l & 15);
    const int k0 = (frag & 31) * 32 + ((l >> 4) << 3) + j0;
    ushort4v u;
    u[0] = f2bf(W[(size_t)(k0 + 0) * D_ + d]);
    u[1] = f2bf(W[(size_t)(k0 + 1) * D_ + d]);
    u[2] = f2bf(W[(size_t)(k0 + 2) * D_ + d]);
    u[3] = f2bf(W[(size_t)(k0 + 3) * D_ + d]);
    *(ushort4v*)(BdT + o) = u;
  }
}

union SMemM {
  struct { float xs[16][128]; float redp[4][16]; } px;
  struct { float redp[4][16]; } zw;
  struct {
    unsigned short xtile[16 * 1024];   // 32 KB, XOR-swizzled (low-4 granule bits)
    float redk[4][2][16][16];          // 8 KB: per-wave K-partials
    float tsum[16][32];                // 2 KB
  } pw;
};

// ============ Kmm2: MFMA prep (128 blocks x 256) ============
// [0,64)   : pxw  (verified round-15 body)
// [64,96)  : zw   (verified round-15 body)
// [96,128) : pwx GEMM — logits2 = x@W + bvec; w*lg - softplus; reduce d
__global__ __launch_bounds__(256) void Kmm2(
    const float* __restrict__ w, const float* __restrict__ z,
    const float* __restrict__ x, const float* __restrict__ cvec,
    const float* __restrict__ bvec, const float* __restrict__ b1,
    const float* __restrict__ W2,
    const unsigned short* __restrict__ Bp, const unsigned short* __restrict__ Bz,
    const unsigned short* __restrict__ BwT, const unsigned short* __restrict__ BdT,
    float* __restrict__ zb1, float* __restrict__ pxw_part,
    float* __restrict__ fzw_part, float* __restrict__ pwx_part) {
  __shared__ SMemM sm;
  const int blk = blockIdx.x;
  const int t = threadIdx.x;
  const int lane = t & 63, wv = t >> 6;

  if (blk < 64) {
    // ================= pxw (verified) =================
    const int bt = blk >> 3, ic = blk & 7;
    {
      const int row = t >> 4, c8 = (t & 15) * 8;
      const float* __restrict__ src = x + (size_t)(bt * 16 + row) * IN_ + ic * 128 + c8;
      *(float4*)&sm.px.xs[row][c8]     = *(const float4*)(src);
      *(float4*)&sm.px.xs[row][c8 + 4] = *(const float4*)(src + 4);
    }
    short8v a[4];
    const int arow = bt * 16 + (lane & 15);
    const int k0 = (lane >> 4) * 8;
    #pragma unroll
    for (int ks = 0; ks < 4; ++ks)
      a[ks] = ld_frag8(w + (size_t)arow * D_ + ks * 32 + k0);
    __syncthreads();

    float term[4] = {0.f, 0.f, 0.f, 0.f};
    #pragma unroll
    for (int itl = 0; itl < 2; ++itl) {
      const int itile = wv * 2 + itl;
      const int git = ic * 8 + itile;
      f32x4 acc = {0.f, 0.f, 0.f, 0.f};
      #pragma unroll
      for (int ks = 0; ks < 4; ++ks) {
        const short8v bfr = *(const short8v*)(BwT + ((size_t)(git * 4 + ks) << 9) + (lane << 3));
        acc = __builtin_amdgcn_mfma_f32_16x16x32_bf16(a[ks], bfr, acc, 0, 0, 0);
      }
      const int iloc = itile * 16 + (lane & 15);
      const float cv = cvec[ic * 128 + iloc];
      #pragma unroll
      for (int j = 0; j < 4; ++j) {
        const int rloc = (lane >> 4) * 4 + j;
        const float lg = acc[j] + cv;
        term[j] += sm.px.xs[rloc][iloc] * lg - softplusf(lg);
      }
    }
    #pragma unroll
    for (int j = 0; j < 4; ++j) {
      float v = term[j];
      v += __shfl_xor(v, 1); v += __shfl_xor(v, 2);
      v += __shfl_xor(v, 4); v += __shfl_xor(v, 8);
      if ((lane & 15) == 0) sm.px.redp[wv][(lane >> 4) * 4 + j] = v;
    }
    __syncthreads();
    if (t < 16)
      pxw_part[(size_t)(bt * 16 + t) * 8 + ic] =
          sm.px.redp[0][t] + sm.px.redp[1][t] + sm.px.redp[2][t] + sm.px.redp[3][t];
  } else if (blk < 96) {
    // ================= zw (verified) =================
    const int bb = blk - 64;
    const int bt = bb >> 2, hc = bb & 3;
    short8v az[4], aw[4];
    const int arow = bt * 16 + (lane & 15);
    const int k0 = (lane >> 4) * 8;
    #pragma unroll
    for (int ks = 0; ks < 4; ++ks) {
      az[ks] = ld_frag8(z + (size_t)arow * D_ + ks * 32 + k0);
      aw[ks] = ld_frag8(w + (size_t)arow * D_ + ks * 32 + k0);
    }
    float term[4] = {0.f, 0.f, 0.f, 0.f};
    #pragma unroll
    for (int htl = 0; htl < 2; ++htl) {
      const int ghb = hc * 8 + wv * 2 + htl;
      f32x4 accz = {0.f, 0.f, 0.f, 0.f};
      f32x4 accw = {0.f, 0.f, 0.f, 0.f};
      #pragma unroll
      for (int ks = 0; ks < 4; ++ks) {
        const size_t fo = ((size_t)(ghb * 4 + ks) << 9) + (lane << 3);
        const short8v bz = *(const short8v*)(Bz + fo);
        const short8v bw = *(const short8v*)(Bp + fo);
        accz = __builtin_amdgcn_mfma_f32_16x16x32_bf16(az[ks], bz, accz, 0, 0, 0);
        accw = __builtin_amdgcn_mfma_f32_16x16x32_bf16(aw[ks], bw, accw, 0, 0, 0);
      }
      const int h = ghb * 16 + (lane & 15);
      const float b1v = b1[h], w2v = W2[h];
      #pragma unroll
      for (int j = 0; j < 4; ++j) {
        const int brow = bt * 16 + (lane >> 4) * 4 + j;
        const float zp = accz[j] + b1v;
        zb1[(size_t)brow * H_ + h] = zp;
        term[j] += fmaxf(zp + accw[j], 0.f) * w2v;
      }
    }
    #pragma unroll
    for (int j = 0; j < 4; ++j) {
      float v = term[j];
      v += __shfl_xor(v, 1); v += __shfl_xor(v, 2);
      v += __shfl_xor(v, 4); v += __shfl_xor(v, 8);
      if ((lane & 15) == 0) sm.zw.redp[wv][(lane >> 4) * 4 + j] = v;
    }
    __syncthreads();
    if (t < 16)
      fzw_part[(size_t)(bt * 16 + t) * 4 + hc] =
          sm.zw.redp[0][t] + sm.zw.redp[1][t] + sm.zw.redp[2][t] + sm.zw.redp[3][t];
  } else {
    // ================= pwx GEMM (NEW) =================
    const int bb = blk - 96;
    const int bt = bb >> 2, dp = bb & 3;     // bt 0..7, dp 0..3 (2 d-tiles each)
    // stage x[16 rows][1024 i] bf16, XOR-swizzle low-4 granule bits with row
    {
      const int r = t >> 4;
      const int gbase = (t & 15) * 8;
      const float* __restrict__ src = x + (size_t)(bt * 16 + r) * IN_;
      #pragma unroll
      for (int gg = 0; gg < 8; ++gg) {
        const int g = gbase + gg;
        const float4 v0 = *(const float4*)(src + g * 8);
        const float4 v1 = *(const float4*)(src + g * 8 + 4);
        ushort8v u;
        u[0] = f2bf(v0.x); u[1] = f2bf(v0.y); u[2] = f2bf(v0.z); u[3] = f2bf(v0.w);
        u[4] = f2bf(v1.x); u[5] = f2bf(v1.y); u[6] = f2bf(v1.z); u[7] = f2bf(v1.w);
        const int gs = (g & ~15) | ((g & 15) ^ (r & 15));
        *(ushort8v*)&sm.pw.xtile[r * 1024 + gs * 8] = u;
      }
    }
    __syncthreads();

    // wave wv: K-quarter [wv*256, wv*256+256), 2 d-tiles
    f32x4 acc0 = {0.f, 0.f, 0.f, 0.f}, acc1 = {0.f, 0.f, 0.f, 0.f};
    const int r = lane & 15;
    #pragma unroll
    for (int kk = 0; kk < 8; ++kk) {
      const int ks = wv * 8 + kk;          // global k-step 0..31
      const int g = ks * 4 + (lane >> 4);
      const int gs = (g & ~15) | ((g & 15) ^ r);
      const short8v a = *(const short8v*)&sm.pw.xtile[r * 1024 + gs * 8];
      const short8v b0 = *(const short8v*)(BdT + ((size_t)((dp * 2 + 0) * 32 + ks) << 9) + (lane << 3));
      const short8v b1f = *(const short8v*)(BdT + ((size_t)((dp * 2 + 1) * 32 + ks) << 9) + (lane << 3));
      acc0 = __builtin_amdgcn_mfma_f32_16x16x32_bf16(a, b0, acc0, 0, 0, 0);
      acc1 = __builtin_amdgcn_mfma_f32_16x16x32_bf16(a, b1f, acc1, 0, 0, 0);
    }
    // per-wave K-partials -> LDS (C layout: row=(lane>>4)*4+j, col=lane&15)
    #pragma unroll
    for (int j = 0; j < 4; ++j) {
      sm.pw.redk[wv][0][(lane >> 4) * 4 + j][lane & 15] = acc0[j];
      sm.pw.redk[wv][1][(lane >> 4) * 4 + j][lane & 15] = acc1[j];
    }
    __syncthreads();
    // combine K + epilogue: 512 elems, 2 per thread
    #pragma unroll
    for (int ee = 0; ee < 2; ++ee) {
      const int e = t + ee * 256;
      const int dt = e >> 8, row = (e >> 4) & 15, col = e & 15;
      const int d = (dp * 2 + dt) * 16 + col;
      const int bglob = bt * 16 + row;
      const float lg = sm.pw.redk[0][dt][row][col] + sm.pw.redk[1][dt][row][col]
                     + sm.pw.redk[2][dt][row][col] + sm.pw.redk[3][dt][row][col]
                     + bvec[d];
      sm.pw.tsum[row][dt * 16 + col] = w[(size_t)bglob * D_ + d] * lg - softplusf(lg);
    }
    __syncthreads();
    if (t < 16) {
      float s = 0.f;
      #pragma unroll
      for (int dd = 0; dd < 32; ++dd) s += sm.pw.tsum[t][dd];
      pwx_part[(size_t)(bt * 16 + t) * 4 + dp] = s;
    }
  }
}

// ============ main fused kernel: one block per b ============
__global__ __launch_bounds__(1024) void Kmain(
    const float* __restrict__ wt, const unsigned short* __restrict__ Bp,
    const float* __restrict__ zb1, const float* __restrict__ W2,
    const float* __restrict__ b2, const float* __restrict__ pxw_part,
    const float* __restrict__ fzw_part, const float* __restrict__ pwx_part,
    float* __restrict__ out) {
  const int b = blockIdx.x;
  const int t = threadIdx.x;
  const int lane = t & 63, wvid = t >> 6;      // wave 0..15
  const int sc = wvid >> 2, nh = (wvid >> 1) & 1, nth = wvid & 1;

  __shared__ unsigned short atile[256 * 128];  // 64 KB, XOR-swizzled bf16
  __shared__ float zb1s[H_];
  __shared__ float w2s[H_];
  __shared__ float red[16][64];
  __shared__ float mred[4], ered[4], miscs[3];

  if (t < 512) { zb1s[t] = zb1[(size_t)b * H_ + t]; w2s[t] = W2[t]; }

  {
    const int r = t >> 2;
    const int g0 = (t & 3) * 4;
    const float* __restrict__ src = wt + ((size_t)r * B_ + b) * D_;
    #pragma unroll
    for (int gg = 0; gg < 4; ++gg) {
      const int g = g0 + gg;
      const float4 v0 = *(const float4*)(src + g * 8);
      const float4 v1 = *(const float4*)(src + g * 8 + 4);
      ushort8v u;
      u[0] = f2bf(v0.x); u[1] = f2bf(v0.y); u[2] = f2bf(v0.z); u[3] = f2bf(v0.w);
      u[4] = f2bf(v1.x); u[5] = f2bf(v1.y); u[6] = f2bf(v1.z); u[7] = f2bf(v1.w);
      *(ushort8v*)&atile[r * 128 + ((g ^ (r & 15)) << 3)] = u;
    }
  }
  __syncthreads();

  short8v afr[4][4];
  #pragma unroll
  for (int m = 0; m < 4; ++m) {
    const int arow = sc * 64 + m * 16 + (lane & 15);
    #pragma unroll
    for (int ks = 0; ks < 4; ++ks) {
      const int g = ks * 4 + (lane >> 4);
      afr[m][ks] = *(const short8v*)&atile[arow * 128 + ((g ^ (arow & 15)) << 3)];
    }
  }

  float fsum[4][4];
  #pragma unroll
  for (int m = 0; m < 4; ++m)
    #pragma unroll
    for (int j = 0; j < 4; ++j) fsum[m][j] = 0.f;

  const int hl = lane & 15;
  #pragma unroll 2
  for (int nt = 0; nt < 8; ++nt) {
    const int hblk = nh * 16 + nth * 8 + nt;
    const int hrow = hblk * 16 + hl;
    f32x4 acc0 = {0.f,0.f,0.f,0.f}, acc1 = {0.f,0.f,0.f,0.f};
    f32x4 acc2 = {0.f,0.f,0.f,0.f}, acc3 = {0.f,0.f,0.f,0.f};
    #pragma unroll
    for (int ks = 0; ks < 4; ++ks) {
      const int frag = hblk * 4 + ks;
      const short8v bfr = *(const short8v*)(Bp + ((size_t)frag << 9) + (lane << 3));
      acc0 = __builtin_amdgcn_mfma_f32_16x16x32_bf16(afr[0][ks], bfr, acc0, 0, 0, 0);
      acc1 = __builtin_amdgcn_mfma_f32_16x16x32_bf16(afr[1][ks], bfr, acc1, 0, 0, 0);
      acc2 = __builtin_amdgcn_mfma_f32_16x16x32_bf16(afr[2][ks], bfr, acc2, 0, 0, 0);
      acc3 = __builtin_amdgcn_mfma_f32_16x16x32_bf16(afr[3][ks], bfr, acc3, 0, 0, 0);
    }
    const float zv = zb1s[hrow], wgt = w2s[hrow];
    #pragma unroll
    for (int j = 0; j < 4; ++j) {
      fsum[0][j] += fmaxf(acc0[j] + zv, 0.f) * wgt;
      fsum[1][j] += fmaxf(acc1[j] + zv, 0.f) * wgt;
      fsum[2][j] += fmaxf(acc2[j] + zv, 0.f) * wgt;
      fsum[3][j] += fmaxf(acc3[j] + zv, 0.f) * wgt;
    }
  }
  #pragma unroll
  for (int m = 0; m < 4; ++m)
    #pragma unroll
    for (int j = 0; j < 4; ++j) {
      float v = fsum[m][j];
      v += __shfl_xor(v, 1); v += __shfl_xor(v, 2);
      v += __shfl_xor(v, 4); v += __shfl_xor(v, 8);
      fsum[m][j] = v;
    }
  if (hl == 0) {
    const int rb = (lane >> 4) * 4;
    #pragma unroll
    for (int m = 0; m < 4; ++m)
      #pragma unroll
      for (int j = 0; j < 4; ++j)
        red[wvid][m * 16 + rb + j] = fsum[m][j];
  }
  __syncthreads();

  float fval = 0.f;
  if (t < 256) {
    const int sc2 = t >> 6, r = t & 63;
    fval = red[sc2 * 4 + 0][r] + red[sc2 * 4 + 1][r]
         + red[sc2 * 4 + 2][r] + red[sc2 * 4 + 3][r] + b2[0];
    float mm = fval;
    #pragma unroll
    for (int o = 1; o < 64; o <<= 1) mm = fmaxf(mm, __shfl_xor(mm, o));
    if (lane == 0) mred[wvid] = mm;
  } else if (t == 256) {
    float s = 0.f;
    #pragma unroll
    for (int ic = 0; ic < 8; ++ic) s += pxw_part[(size_t)b * 8 + ic];
    miscs[0] = s;
  } else if (t == 257) {
    float s = 0.f;
    #pragma unroll
    for (int hc = 0; hc < 4; ++hc) s += fzw_part[(size_t)b * 4 + hc];
    miscs[1] = s;
  } else if (t == 258) {
    float s = 0.f;
    #pragma unroll
    for (int dp = 0; dp < 4; ++dp) s += pwx_part[(size_t)b * 4 + dp];
    miscs[2] = s;
  }
  __syncthreads();
  if (t < 256) {
    const float mm = fmaxf(fmaxf(mred[0], mred[1]), fmaxf(mred[2], mred[3]));
    float e = expf(fval - mm);
    #pragma unroll
    for (int o = 1; o < 64; o <<= 1) e += __shfl_xor(e, o);
    if (lane == 0) ered[wvid] = e;
  }
  __syncthreads();
  if (t == 0) {
    const float mm = fmaxf(fmaxf(mred[0], mred[1]), fmaxf(mred[2], mred[3]));
    const float tot = ered[0] + ered[1] + ered[2] + ered[3];
    const float logZ = mm + logf(tot) - logf((float)S_) + (float)D_ * logf(2.f);
    const float pxw = miscs[0];
    const float fzw = miscs[1] + b2[0];
    const float pwx = miscs[2];
    const float r_wz = fminf(fzw - logZ, 0.f);
    out[b] = -(pxw - pwx + r_wz);
  }
}

extern "C" void kernel_launch(void* const* d_in, const int* in_sizes, int n_in,
                              void* d_out, int out_size, void* d_ws, size_t ws_size,
                              hipStream_t stream) {
  const float* x    = (const float*)d_in[0];
  // d_in[1] = y, unused
  const float* w    = (const float*)d_in[2];
  const float* z    = (const float*)d_in[3];
  const float* wt   = (const float*)d_in[4];
  const float* W    = (const float*)d_in[5];
  const float* bvec = (const float*)d_in[6];
  const float* cvec = (const float*)d_in[7];
  const float* W1   = (const float*)d_in[8];
  const float* b1   = (const float*)d_in[9];
  const float* W2   = (const float*)d_in[10];
  const float* b2   = (const float*)d_in[11];

  float* ws_f = (float*)d_ws;
  unsigned short* Bp    = (unsigned short*)ws_f;              // 65536 us = 32768 f
  unsigned short* Bz    = (unsigned short*)(ws_f + 32768);    // 65536 us
  unsigned short* BwT   = (unsigned short*)(ws_f + 65536);    // 131072 us = 65536 f
  unsigned short* BdT   = (unsigned short*)(ws_f + 131072);   // 131072 us = 65536 f
  float* zb1            = ws_f + 196608;                      // 65536 f
  float* pxw_part       = ws_f + 262144;                      // 1024 f
  float* fzw_part       = ws_f + 263168;                      // 512 f
  float* pwx_part       = ws_f + 263680;                      // 512 f
  float* out = (float*)d_out;

  hipLaunchKernelGGL(Kpack2, dim3(384), dim3(256), 0, stream,
                     W, W1, Bp, Bz, BwT, BdT);
  hipLaunchKernelGGL(Kmm2, dim3(128), dim3(256), 0, stream,
                     w, z, x, cvec, bvec, b1, W2, Bp, Bz, BwT, BdT,
                     zb1, pxw_part, fzw_part, pwx_part);
  hipLaunchKernelGGL(Kmain, dim3(B_), dim3(1024), 0, stream,
                     wt, Bp, zb1, W2, b2, pxw_part, fzw_part, pwx_part, out);
}

// Round 17
// 30.721 us; speedup vs baseline: 1.1037x; 1.1037x over previous
//
#include <hip/hip_runtime.h>
#include <hip/hip_bf16.h>
#include <math.h>

#define B_ 128
#define IN_ 1024
#define D_ 128
#define H_ 512
#define S_ 256

typedef __attribute__((ext_vector_type(8))) short short8v;
typedef __attribute__((ext_vector_type(8))) unsigned short ushort8v;
typedef __attribute__((ext_vector_type(4))) unsigned short ushort4v;
typedef __attribute__((ext_vector_type(4))) float f32x4;

__device__ __forceinline__ float softplusf(float x) {
  return fmaxf(x, 0.f) + log1pf(expf(-fabsf(x)));
}

__device__ __forceinline__ unsigned short f2bf(float f) {
  unsigned u = __float_as_uint(f);
  unsigned r = (u + 0x7fff + ((u >> 16) & 1)) >> 16;   // RNE
  return (unsigned short)r;
}

// load 8 consecutive fp32 at p, convert to bf16 fragment
__device__ __forceinline__ short8v ld_frag8(const float* __restrict__ p) {
  const float4 v0 = *(const float4*)(p);
  const float4 v1 = *(const float4*)(p + 4);
  short8v s;
  s[0] = (short)f2bf(v0.x); s[1] = (short)f2bf(v0.y);
  s[2] = (short)f2bf(v0.z); s[3] = (short)f2bf(v0.w);
  s[4] = (short)f2bf(v1.x); s[5] = (short)f2bf(v1.y);
  s[6] = (short)f2bf(v1.z); s[7] = (short)f2bf(v1.w);
  return s;
}

union SMemP {
  struct { float xs[16][128]; float redp[4][16]; } px;
  struct { float redp[4][16]; } zw;
  struct { float xs[128]; float p2[256]; } pw;
};

// ============ Kprep3: all prep in one kernel (1184 blocks x 256) ============
// [0,64)      : Bp pack (verified)
// [64,128)    : pxw MFMA, inline W fragments (value-identical to BwT path)
// [128,160)   : zw MFMA, inline W1 fragments (value-identical to Bz/Bp path)
// [160,1184)  : pwx partial logits (R15 verbatim)
__global__ __launch_bounds__(256) void Kprep3(
    const float* __restrict__ x, const float* __restrict__ w,
    const float* __restrict__ z, const float* __restrict__ W,
    const float* __restrict__ cvec, const float* __restrict__ W1,
    const float* __restrict__ b1, const float* __restrict__ W2,
    unsigned short* __restrict__ Bp, float* __restrict__ l2part,
    float* __restrict__ zb1, float* __restrict__ pxw_part,
    float* __restrict__ fzw_part) {
  __shared__ SMemP sm;
  const int blk = blockIdx.x;
  const int t = threadIdx.x;
  const int lane = t & 63, wv = t >> 6;

  if (blk < 64) {
    // ---- Bp pack (verified): frag=hblk*4+ks, h=hblk*16+(l&15), k=ks*32+(l>>4)*8+j
    const int o = (blk * 256 + t) * 4;
    const int frag = o >> 9;
    const int l = (o >> 3) & 63;
    const int j0 = o & 7;
    const int h = (frag >> 2) * 16 + (l & 15);
    const int k0 = (frag & 3) * 32 + ((l >> 4) << 3) + j0;
    const float4 v = *(const float4*)(W1 + (size_t)h * 256 + 128 + k0);
    ushort4v u;
    u[0] = f2bf(v.x); u[1] = f2bf(v.y); u[2] = f2bf(v.z); u[3] = f2bf(v.w);
    *(ushort4v*)(Bp + o) = u;
  } else if (blk < 128) {
    // ================= pxw MFMA (R15 body, inline B-frags) =================
    const int bb = blk - 64;
    const int bt = bb >> 3, ic = bb & 7;
    {
      const int row = t >> 4, c8 = (t & 15) * 8;
      const float* __restrict__ src = x + (size_t)(bt * 16 + row) * IN_ + ic * 128 + c8;
      *(float4*)&sm.px.xs[row][c8]     = *(const float4*)(src);
      *(float4*)&sm.px.xs[row][c8 + 4] = *(const float4*)(src + 4);
    }
    short8v a[4];
    const int arow = bt * 16 + (lane & 15);
    const int k0 = (lane >> 4) * 8;
    #pragma unroll
    for (int ks = 0; ks < 4; ++ks)
      a[ks] = ld_frag8(w + (size_t)arow * D_ + ks * 32 + k0);
    __syncthreads();

    float term[4] = {0.f, 0.f, 0.f, 0.f};
    #pragma unroll
    for (int itl = 0; itl < 2; ++itl) {
      const int itile = wv * 2 + itl;
      const int git = ic * 8 + itile;
      const int irow = git * 16 + (lane & 15);
      f32x4 acc = {0.f, 0.f, 0.f, 0.f};
      #pragma unroll
      for (int ks = 0; ks < 4; ++ks) {
        const short8v bfr = ld_frag8(W + (size_t)irow * D_ + ks * 32 + k0);
        acc = __builtin_amdgcn_mfma_f32_16x16x32_bf16(a[ks], bfr, acc, 0, 0, 0);
      }
      const int iloc = itile * 16 + (lane & 15);
      const float cv = cvec[ic * 128 + iloc];
      #pragma unroll
      for (int j = 0; j < 4; ++j) {
        const int rloc = (lane >> 4) * 4 + j;
        const float lg = acc[j] + cv;
        term[j] += sm.px.xs[rloc][iloc] * lg - softplusf(lg);
      }
    }
    #pragma unroll
    for (int j = 0; j < 4; ++j) {
      float v = term[j];
      v += __shfl_xor(v, 1); v += __shfl_xor(v, 2);
      v += __shfl_xor(v, 4); v += __shfl_xor(v, 8);
      if ((lane & 15) == 0) sm.px.redp[wv][(lane >> 4) * 4 + j] = v;
    }
    __syncthreads();
    if (t < 16)
      pxw_part[(size_t)(bt * 16 + t) * 8 + ic] =
          sm.px.redp[0][t] + sm.px.redp[1][t] + sm.px.redp[2][t] + sm.px.redp[3][t];
  } else if (blk < 160) {
    // ================= zw MFMA (R15 body, inline B-frags) =================
    const int bb = blk - 128;
    const int bt = bb >> 2, hc = bb & 3;
    short8v az[4], aw[4];
    const int arow = bt * 16 + (lane & 15);
    const int k0 = (lane >> 4) * 8;
    #pragma unroll
    for (int ks = 0; ks < 4; ++ks) {
      az[ks] = ld_frag8(z + (size_t)arow * D_ + ks * 32 + k0);
      aw[ks] = ld_frag8(w + (size_t)arow * D_ + ks * 32 + k0);
    }
    float term[4] = {0.f, 0.f, 0.f, 0.f};
    #pragma unroll
    for (int htl = 0; htl < 2; ++htl) {
      const int ghb = hc * 8 + wv * 2 + htl;
      const int h = ghb * 16 + (lane & 15);
      f32x4 accz = {0.f, 0.f, 0.f, 0.f};
      f32x4 accw = {0.f, 0.f, 0.f, 0.f};
      #pragma unroll
      for (int ks = 0; ks < 4; ++ks) {
        const short8v bz = ld_frag8(W1 + (size_t)h * 256 + ks * 32 + k0);
        const short8v bw = ld_frag8(W1 + (size_t)h * 256 + 128 + ks * 32 + k0);
        accz = __builtin_amdgcn_mfma_f32_16x16x32_bf16(az[ks], bz, accz, 0, 0, 0);
        accw = __builtin_amdgcn_mfma_f32_16x16x32_bf16(aw[ks], bw, accw, 0, 0, 0);
      }
      const float b1v = b1[h], w2v = W2[h];
      #pragma unroll
      for (int j = 0; j < 4; ++j) {
        const int brow = bt * 16 + (lane >> 4) * 4 + j;
        const float zp = accz[j] + b1v;
        zb1[(size_t)brow * H_ + h] = zp;
        term[j] += fmaxf(zp + accw[j], 0.f) * w2v;
      }
    }
    #pragma unroll
    for (int j = 0; j < 4; ++j) {
      float v = term[j];
      v += __shfl_xor(v, 1); v += __shfl_xor(v, 2);
      v += __shfl_xor(v, 4); v += __shfl_xor(v, 8);
      if ((lane & 15) == 0) sm.zw.redp[wv][(lane >> 4) * 4 + j] = v;
    }
    __syncthreads();
    if (t < 16)
      fzw_part[(size_t)(bt * 16 + t) * 4 + hc] =
          sm.zw.redp[0][t] + sm.zw.redp[1][t] + sm.zw.redp[2][t] + sm.zw.redp[3][t];
  } else {
    // ================= pwx partial (R15 verbatim) =================
    const int bb = blk - 160;
    const int b = bb >> 3, kc = bb & 7;
    float* xs = sm.pw.xs;
    float* p2 = sm.pw.p2;
    if (t < 128) xs[t] = x[b * IN_ + kc * 128 + t];
    __syncthreads();
    const int d = t & 127, ks = t >> 7;
    const float* __restrict__ Wp = W + (size_t)(kc * 128 + ks * 64) * D_ + d;
    float s = 0.f;
    #pragma unroll 8
    for (int i = 0; i < 64; ++i) s = fmaf(xs[ks * 64 + i], Wp[(size_t)i * D_], s);
    p2[ks * 128 + d] = s;
    __syncthreads();
    if (t < 128) l2part[((size_t)b * 8 + kc) * 128 + t] = p2[t] + p2[128 + t];
  }
}

// ============ MFMA GEMM (R7 verbatim): 512 blocks x 256 thr ============
__global__ __launch_bounds__(256) void Kmfma(
    const float* __restrict__ wt, const unsigned short* __restrict__ Bp,
    const float* __restrict__ zb1, const float* __restrict__ W2,
    const float* __restrict__ b2, float* __restrict__ mpart,
    float* __restrict__ lpart) {
  const int blk = blockIdx.x;            // 512 = sq*128 + b
  const int b = blk & (B_ - 1);
  const int sq = blk >> 7;               // 0..3
  const int s0 = sq * 64;
  const int t = threadIdx.x;
  const int lane = t & 63, wv = t >> 6;  // 4 waves

  __shared__ unsigned short atile[64 * 128];   // 16 KB, XOR-swizzled bf16
  __shared__ float zb1s[H_];
  __shared__ float w2s[H_];
  __shared__ float red[4][64];

  zb1s[t] = zb1[(size_t)b * H_ + t];
  zb1s[256 + t] = zb1[(size_t)b * H_ + 256 + t];
  w2s[t] = W2[t];
  w2s[256 + t] = W2[256 + t];

  // stage A: 64 rows x 128 d, fp32 -> bf16, granule swizzle g ^= r&15 (verified)
  {
    const int r = t >> 2;                // 0..63
    const int g0 = (t & 3) * 4;
    const float* __restrict__ src = wt + ((size_t)(s0 + r) * B_ + b) * D_;
    #pragma unroll
    for (int gg = 0; gg < 4; ++gg) {
      const int g = g0 + gg;
      const float4 v0 = *(const float4*)(src + g * 8);
      const float4 v1 = *(const float4*)(src + g * 8 + 4);
      ushort8v u;
      u[0] = f2bf(v0.x); u[1] = f2bf(v0.y); u[2] = f2bf(v0.z); u[3] = f2bf(v0.w);
      u[4] = f2bf(v1.x); u[5] = f2bf(v1.y); u[6] = f2bf(v1.z); u[7] = f2bf(v1.w);
      *(ushort8v*)&atile[r * 128 + ((g ^ (r & 15)) << 3)] = u;
    }
  }
  __syncthreads();

  // A fragments (verified): row = m*16 + (lane&15), k = ks*32 + (lane>>4)*8 + j
  short8v afr[4][4];
  #pragma unroll
  for (int m = 0; m < 4; ++m) {
    const int arow = m * 16 + (lane & 15);
    #pragma unroll
    for (int ks = 0; ks < 4; ++ks) {
      const int g = ks * 4 + (lane >> 4);
      afr[m][ks] = *(const short8v*)&atile[arow * 128 + ((g ^ (arow & 15)) << 3)];
    }
  }

  float fsum[4][4];
  #pragma unroll
  for (int m = 0; m < 4; ++m)
    #pragma unroll
    for (int j = 0; j < 4; ++j) fsum[m][j] = 0.f;

  const int hl = lane & 15;
  #pragma unroll 2
  for (int nt = 0; nt < 8; ++nt) {
    const int hblk = wv * 8 + nt;        // 0..31
    const int hrow = hblk * 16 + hl;
    f32x4 acc0 = {0.f,0.f,0.f,0.f}, acc1 = {0.f,0.f,0.f,0.f};
    f32x4 acc2 = {0.f,0.f,0.f,0.f}, acc3 = {0.f,0.f,0.f,0.f};
    #pragma unroll
    for (int ks = 0; ks < 4; ++ks) {
      const int frag = hblk * 4 + ks;
      const short8v bfr = *(const short8v*)(Bp + ((size_t)frag << 9) + (lane << 3));
      acc0 = __builtin_amdgcn_mfma_f32_16x16x32_bf16(afr[0][ks], bfr, acc0, 0, 0, 0);
      acc1 = __builtin_amdgcn_mfma_f32_16x16x32_bf16(afr[1][ks], bfr, acc1, 0, 0, 0);
      acc2 = __builtin_amdgcn_mfma_f32_16x16x32_bf16(afr[2][ks], bfr, acc2, 0, 0, 0);
      acc3 = __builtin_amdgcn_mfma_f32_16x16x32_bf16(afr[3][ks], bfr, acc3, 0, 0, 0);
    }
    const float zv = zb1s[hrow], wgt = w2s[hrow];
    #pragma unroll
    for (int j = 0; j < 4; ++j) {
      fsum[0][j] += fmaxf(acc0[j] + zv, 0.f) * wgt;
      fsum[1][j] += fmaxf(acc1[j] + zv, 0.f) * wgt;
      fsum[2][j] += fmaxf(acc2[j] + zv, 0.f) * wgt;
      fsum[3][j] += fmaxf(acc3[j] + zv, 0.f) * wgt;
    }
  }
  // reduce over 16 h-columns (lane bits 0..3)
  #pragma unroll
  for (int m = 0; m < 4; ++m)
    #pragma unroll
    for (int j = 0; j < 4; ++j) {
      float v = fsum[m][j];
      v += __shfl_xor(v, 1); v += __shfl_xor(v, 2);
      v += __shfl_xor(v, 4); v += __shfl_xor(v, 8);
      fsum[m][j] = v;
    }
  if (hl == 0) {
    const int rb = (lane >> 4) * 4;
    #pragma unroll
    for (int m = 0; m < 4; ++m)
      #pragma unroll
      for (int j = 0; j < 4; ++j)
        red[wv][m * 16 + rb + j] = fsum[m][j];
  }
  __syncthreads();

  // partial logsumexp over this block's 64 f values
  if (t < 64) {
    const float fval = red[0][t] + red[1][t] + red[2][t] + red[3][t] + b2[0];
    float mm = fval;
    #pragma unroll
    for (int o = 1; o < 64; o <<= 1) mm = fmaxf(mm, __shfl_xor(mm, o));
    float e = expf(fval - mm);
    #pragma unroll
    for (int o = 1; o < 64; o <<= 1) e += __shfl_xor(e, o);
    if (t == 0) { mpart[blk] = mm; lpart[blk] = e; }
  }
}

// ============ finisher (R7 verbatim; partial counts updated): 128 x 128 ============
__global__ __launch_bounds__(128) void Kfin(
    const float* __restrict__ mpart, const float* __restrict__ lpart,
    const float* __restrict__ l2part, const float* __restrict__ bvec,
    const float* __restrict__ w, const float* __restrict__ pxw_part,
    const float* __restrict__ fzw_part, const float* __restrict__ b2,
    float* __restrict__ out) {
  const int b = blockIdx.x, t = threadIdx.x;
  __shared__ float red3[2];
  const int lane = t & 63, wid = t >> 6;
  // pwx finish
  float lg = bvec[t];
  #pragma unroll
  for (int kc = 0; kc < 8; ++kc) lg += l2part[((size_t)b * 8 + kc) * 128 + t];
  float term = w[b * 128 + t] * lg - softplusf(lg);
  #pragma unroll
  for (int o = 1; o < 64; o <<= 1) term += __shfl_xor(term, o);
  if (lane == 0) red3[wid] = term;
  __syncthreads();
  if (t == 0) {
    const float pwx = red3[0] + red3[1];
    // combine 4 logsumexp partials
    const float m0 = mpart[b], m1 = mpart[128 + b],
                m2 = mpart[256 + b], m3 = mpart[384 + b];
    const float mm = fmaxf(fmaxf(m0, m1), fmaxf(m2, m3));
    const float l = lpart[b] * expf(m0 - mm) + lpart[128 + b] * expf(m1 - mm)
                  + lpart[256 + b] * expf(m2 - mm) + lpart[384 + b] * expf(m3 - mm);
    const float logZ = mm + logf(l) - logf((float)S_) + (float)D_ * logf(2.f);
    float pxw = 0.f;
    #pragma unroll
    for (int ic = 0; ic < 8; ++ic) pxw += pxw_part[(size_t)b * 8 + ic];
    float fzw = b2[0];
    #pragma unroll
    for (int hc = 0; hc < 4; ++hc) fzw += fzw_part[(size_t)b * 4 + hc];
    const float r_wz = fminf(fzw - logZ, 0.f);
    out[b] = -(pxw - pwx + r_wz);
  }
}

extern "C" void kernel_launch(void* const* d_in, const int* in_sizes, int n_in,
                              void* d_out, int out_size, void* d_ws, size_t ws_size,
                              hipStream_t stream) {
  const float* x    = (const float*)d_in[0];
  // d_in[1] = y, unused
  const float* w    = (const float*)d_in[2];
  const float* z    = (const float*)d_in[3];
  const float* wt   = (const float*)d_in[4];
  const float* W    = (const float*)d_in[5];
  const float* bvec = (const float*)d_in[6];
  const float* cvec = (const float*)d_in[7];
  const float* W1   = (const float*)d_in[8];
  const float* b1   = (const float*)d_in[9];
  const float* W2   = (const float*)d_in[10];
  const float* b2   = (const float*)d_in[11];

  float* ws_f = (float*)d_ws;
  unsigned short* Bp    = (unsigned short*)ws_f;              // 65536 us = 32768 f
  float* zb1            = ws_f + 32768;                       // 65536 f
  float* l2part         = ws_f + 98304;                       // 131072 f
  float* pxw_part       = ws_f + 229376;                      // 1024 f
  float* fzw_part       = ws_f + 230400;                      // 512 f
  float* mpart          = ws_f + 230912;                      // 512 f
  float* lpart          = ws_f + 231424;                      // 512 f
  float* out = (float*)d_out;

  hipLaunchKernelGGL(Kprep3, dim3(1184), dim3(256), 0, stream,
                     x, w, z, W, cvec, W1, b1, W2, Bp, l2part, zb1, pxw_part, fzw_part);
  hipLaunchKernelGGL(Kmfma, dim3(512), dim3(256), 0, stream,
                     wt, Bp, zb1, W2, b2, mpart, lpart);
  hipLaunchKernelGGL(Kfin, dim3(B_), dim3(128), 0, stream,
                     mpart, lpart, l2part, bvec, w, pxw_part, fzw_part, b2, out);
}

// Round 18
// 26.421 us; speedup vs baseline: 1.2833x; 1.1627x over previous
//
#include <hip/hip_runtime.h>
#include <hip/hip_bf16.h>
#include <math.h>

#define B_ 128
#define IN_ 1024
#define D_ 128
#define H_ 512
#define S_ 256

typedef __attribute__((ext_vector_type(8))) short short8v;
typedef __attribute__((ext_vector_type(8))) unsigned short ushort8v;
typedef __attribute__((ext_vector_type(4))) unsigned short ushort4v;
typedef __attribute__((ext_vector_type(4))) float f32x4;

__device__ __forceinline__ float softplusf(float x) {
  return fmaxf(x, 0.f) + log1pf(expf(-fabsf(x)));
}

__device__ __forceinline__ unsigned short f2bf(float f) {
  unsigned u = __float_as_uint(f);
  unsigned r = (u + 0x7fff + ((u >> 16) & 1)) >> 16;   // RNE
  return (unsigned short)r;
}

// load 8 consecutive fp32 at p, convert to bf16 fragment
__device__ __forceinline__ short8v ld_frag8(const float* __restrict__ p) {
  const float4 v0 = *(const float4*)(p);
  const float4 v1 = *(const float4*)(p + 4);
  short8v s;
  s[0] = (short)f2bf(v0.x); s[1] = (short)f2bf(v0.y);
  s[2] = (short)f2bf(v0.z); s[3] = (short)f2bf(v0.w);
  s[4] = (short)f2bf(v1.x); s[5] = (short)f2bf(v1.y);
  s[6] = (short)f2bf(v1.z); s[7] = (short)f2bf(v1.w);
  return s;
}

union SMemP {
  struct { float xs[16][128]; float redp[4][16]; } px;
  struct { float redp[4][16]; } zw;
  struct { float xs[64]; float p2[256]; } pw;
};

// ============ Kprep3: all prep in one kernel (2208 blocks x 256) ============
// [0,64)      : Bp pack (verified)
// [64,128)    : pxw MFMA, inline W fragments (verified R17)
// [128,160)   : zw MFMA, inline W1 fragments (verified R17)
// [160,2208)  : pwx partial logits — split 2x vs R17 (64 i-rows, kc of 16)
__global__ __launch_bounds__(256) void Kprep3(
    const float* __restrict__ x, const float* __restrict__ w,
    const float* __restrict__ z, const float* __restrict__ W,
    const float* __restrict__ cvec, const float* __restrict__ W1,
    const float* __restrict__ b1, const float* __restrict__ W2,
    unsigned short* __restrict__ Bp, float* __restrict__ l2part,
    float* __restrict__ zb1, float* __restrict__ pxw_part,
    float* __restrict__ fzw_part) {
  __shared__ SMemP sm;
  const int blk = blockIdx.x;
  const int t = threadIdx.x;
  const int lane = t & 63, wv = t >> 6;

  if (blk < 64) {
    // ---- Bp pack (verified)
    const int o = (blk * 256 + t) * 4;
    const int frag = o >> 9;
    const int l = (o >> 3) & 63;
    const int j0 = o & 7;
    const int h = (frag >> 2) * 16 + (l & 15);
    const int k0 = (frag & 3) * 32 + ((l >> 4) << 3) + j0;
    const float4 v = *(const float4*)(W1 + (size_t)h * 256 + 128 + k0);
    ushort4v u;
    u[0] = f2bf(v.x); u[1] = f2bf(v.y); u[2] = f2bf(v.z); u[3] = f2bf(v.w);
    *(ushort4v*)(Bp + o) = u;
  } else if (blk < 128) {
    // ================= pxw MFMA (verified R17) =================
    const int bb = blk - 64;
    const int bt = bb >> 3, ic = bb & 7;
    {
      const int row = t >> 4, c8 = (t & 15) * 8;
      const float* __restrict__ src = x + (size_t)(bt * 16 + row) * IN_ + ic * 128 + c8;
      *(float4*)&sm.px.xs[row][c8]     = *(const float4*)(src);
      *(float4*)&sm.px.xs[row][c8 + 4] = *(const float4*)(src + 4);
    }
    short8v a[4];
    const int arow = bt * 16 + (lane & 15);
    const int k0 = (lane >> 4) * 8;
    #pragma unroll
    for (int ks = 0; ks < 4; ++ks)
      a[ks] = ld_frag8(w + (size_t)arow * D_ + ks * 32 + k0);
    __syncthreads();

    float term[4] = {0.f, 0.f, 0.f, 0.f};
    #pragma unroll
    for (int itl = 0; itl < 2; ++itl) {
      const int itile = wv * 2 + itl;
      const int git = ic * 8 + itile;
      const int irow = git * 16 + (lane & 15);
      f32x4 acc = {0.f, 0.f, 0.f, 0.f};
      #pragma unroll
      for (int ks = 0; ks < 4; ++ks) {
        const short8v bfr = ld_frag8(W + (size_t)irow * D_ + ks * 32 + k0);
        acc = __builtin_amdgcn_mfma_f32_16x16x32_bf16(a[ks], bfr, acc, 0, 0, 0);
      }
      const int iloc = itile * 16 + (lane & 15);
      const float cv = cvec[ic * 128 + iloc];
      #pragma unroll
      for (int j = 0; j < 4; ++j) {
        const int rloc = (lane >> 4) * 4 + j;
        const float lg = acc[j] + cv;
        term[j] += sm.px.xs[rloc][iloc] * lg - softplusf(lg);
      }
    }
    #pragma unroll
    for (int j = 0; j < 4; ++j) {
      float v = term[j];
      v += __shfl_xor(v, 1); v += __shfl_xor(v, 2);
      v += __shfl_xor(v, 4); v += __shfl_xor(v, 8);
      if ((lane & 15) == 0) sm.px.redp[wv][(lane >> 4) * 4 + j] = v;
    }
    __syncthreads();
    if (t < 16)
      pxw_part[(size_t)(bt * 16 + t) * 8 + ic] =
          sm.px.redp[0][t] + sm.px.redp[1][t] + sm.px.redp[2][t] + sm.px.redp[3][t];
  } else if (blk < 160) {
    // ================= zw MFMA (verified R17) =================
    const int bb = blk - 128;
    const int bt = bb >> 2, hc = bb & 3;
    short8v az[4], aw[4];
    const int arow = bt * 16 + (lane & 15);
    const int k0 = (lane >> 4) * 8;
    #pragma unroll
    for (int ks = 0; ks < 4; ++ks) {
      az[ks] = ld_frag8(z + (size_t)arow * D_ + ks * 32 + k0);
      aw[ks] = ld_frag8(w + (size_t)arow * D_ + ks * 32 + k0);
    }
    float term[4] = {0.f, 0.f, 0.f, 0.f};
    #pragma unroll
    for (int htl = 0; htl < 2; ++htl) {
      const int ghb = hc * 8 + wv * 2 + htl;
      const int h = ghb * 16 + (lane & 15);
      f32x4 accz = {0.f, 0.f, 0.f, 0.f};
      f32x4 accw = {0.f, 0.f, 0.f, 0.f};
      #pragma unroll
      for (int ks = 0; ks < 4; ++ks) {
        const short8v bz = ld_frag8(W1 + (size_t)h * 256 + ks * 32 + k0);
        const short8v bw = ld_frag8(W1 + (size_t)h * 256 + 128 + ks * 32 + k0);
        accz = __builtin_amdgcn_mfma_f32_16x16x32_bf16(az[ks], bz, accz, 0, 0, 0);
        accw = __builtin_amdgcn_mfma_f32_16x16x32_bf16(aw[ks], bw, accw, 0, 0, 0);
      }
      const float b1v = b1[h], w2v = W2[h];
      #pragma unroll
      for (int j = 0; j < 4; ++j) {
        const int brow = bt * 16 + (lane >> 4) * 4 + j;
        const float zp = accz[j] + b1v;
        zb1[(size_t)brow * H_ + h] = zp;
        term[j] += fmaxf(zp + accw[j], 0.f) * w2v;
      }
    }
    #pragma unroll
    for (int j = 0; j < 4; ++j) {
      float v = term[j];
      v += __shfl_xor(v, 1); v += __shfl_xor(v, 2);
      v += __shfl_xor(v, 4); v += __shfl_xor(v, 8);
      if ((lane & 15) == 0) sm.zw.redp[wv][(lane >> 4) * 4 + j] = v;
    }
    __syncthreads();
    if (t < 16)
      fzw_part[(size_t)(bt * 16 + t) * 4 + hc] =
          sm.zw.redp[0][t] + sm.zw.redp[1][t] + sm.zw.redp[2][t] + sm.zw.redp[3][t];
  } else {
    // ================= pwx partial (split 2x: 64 i-rows per block) =================
    const int bb = blk - 160;
    const int b = bb >> 4, kc = bb & 15;
    float* xs = sm.pw.xs;
    float* p2 = sm.pw.p2;
    if (t < 64) xs[t] = x[b * IN_ + kc * 64 + t];
    __syncthreads();
    const int d = t & 127, ks = t >> 7;
    const float* __restrict__ Wp = W + (size_t)(kc * 64 + ks * 32) * D_ + d;
    float s = 0.f;
    #pragma unroll 8
    for (int i = 0; i < 32; ++i) s = fmaf(xs[ks * 32 + i], Wp[(size_t)i * D_], s);
    p2[ks * 128 + d] = s;
    __syncthreads();
    if (t < 128) l2part[((size_t)b * 16 + kc) * 128 + t] = p2[t] + p2[128 + t];
  }
}

// ============ MFMA GEMM: 1024 blocks x 256 thr, block = (b, s-eighth of 32) ============
__global__ __launch_bounds__(256) void Kmfma(
    const float* __restrict__ wt, const unsigned short* __restrict__ Bp,
    const float* __restrict__ zb1, const float* __restrict__ W2,
    const float* __restrict__ b2, float* __restrict__ mpart,
    float* __restrict__ lpart) {
  const int blk = blockIdx.x;            // 1024 = sq*128 + b
  const int b = blk & (B_ - 1);
  const int sq = blk >> 7;               // 0..7
  const int s0 = sq * 32;
  const int t = threadIdx.x;
  const int lane = t & 63, wv = t >> 6;  // 4 waves

  __shared__ unsigned short atile[32 * 128];   // 8 KB, XOR-swizzled bf16
  __shared__ float zb1s[H_];
  __shared__ float w2s[H_];
  __shared__ float red[4][32];

  zb1s[t] = zb1[(size_t)b * H_ + t];
  zb1s[256 + t] = zb1[(size_t)b * H_ + 256 + t];
  w2s[t] = W2[t];
  w2s[256 + t] = W2[256 + t];

  // stage A: 32 rows x 128 d, fp32 -> bf16, granule swizzle g ^= r&15 (verified)
  {
    const int r = t >> 3;                // 0..31
    const int g0 = (t & 7) * 2;
    const float* __restrict__ src = wt + ((size_t)(s0 + r) * B_ + b) * D_;
    #pragma unroll
    for (int gg = 0; gg < 2; ++gg) {
      const int g = g0 + gg;
      const float4 v0 = *(const float4*)(src + g * 8);
      const float4 v1 = *(const float4*)(src + g * 8 + 4);
      ushort8v u;
      u[0] = f2bf(v0.x); u[1] = f2bf(v0.y); u[2] = f2bf(v0.z); u[3] = f2bf(v0.w);
      u[4] = f2bf(v1.x); u[5] = f2bf(v1.y); u[6] = f2bf(v1.z); u[7] = f2bf(v1.w);
      *(ushort8v*)&atile[r * 128 + ((g ^ (r & 15)) << 3)] = u;
    }
  }
  __syncthreads();

  // A fragments (verified mapping): row = m*16 + (lane&15)
  short8v afr[2][4];
  #pragma unroll
  for (int m = 0; m < 2; ++m) {
    const int arow = m * 16 + (lane & 15);
    #pragma unroll
    for (int ks = 0; ks < 4; ++ks) {
      const int g = ks * 4 + (lane >> 4);
      afr[m][ks] = *(const short8v*)&atile[arow * 128 + ((g ^ (arow & 15)) << 3)];
    }
  }

  float fsum[2][4];
  #pragma unroll
  for (int m = 0; m < 2; ++m)
    #pragma unroll
    for (int j = 0; j < 4; ++j) fsum[m][j] = 0.f;

  const int hl = lane & 15;
  #pragma unroll 2
  for (int nt = 0; nt < 8; ++nt) {
    const int hblk = wv * 8 + nt;        // 0..31
    const int hrow = hblk * 16 + hl;
    f32x4 acc0 = {0.f,0.f,0.f,0.f}, acc1 = {0.f,0.f,0.f,0.f};
    #pragma unroll
    for (int ks = 0; ks < 4; ++ks) {
      const int frag = hblk * 4 + ks;
      const short8v bfr = *(const short8v*)(Bp + ((size_t)frag << 9) + (lane << 3));
      acc0 = __builtin_amdgcn_mfma_f32_16x16x32_bf16(afr[0][ks], bfr, acc0, 0, 0, 0);
      acc1 = __builtin_amdgcn_mfma_f32_16x16x32_bf16(afr[1][ks], bfr, acc1, 0, 0, 0);
    }
    const float zv = zb1s[hrow], wgt = w2s[hrow];
    #pragma unroll
    for (int j = 0; j < 4; ++j) {
      fsum[0][j] += fmaxf(acc0[j] + zv, 0.f) * wgt;
      fsum[1][j] += fmaxf(acc1[j] + zv, 0.f) * wgt;
    }
  }
  // reduce over 16 h-columns (lane bits 0..3)
  #pragma unroll
  for (int m = 0; m < 2; ++m)
    #pragma unroll
    for (int j = 0; j < 4; ++j) {
      float v = fsum[m][j];
      v += __shfl_xor(v, 1); v += __shfl_xor(v, 2);
      v += __shfl_xor(v, 4); v += __shfl_xor(v, 8);
      fsum[m][j] = v;
    }
  if (hl == 0) {
    const int rb = (lane >> 4) * 4;
    #pragma unroll
    for (int m = 0; m < 2; ++m)
      #pragma unroll
      for (int j = 0; j < 4; ++j)
        red[wv][m * 16 + rb + j] = fsum[m][j];
  }
  __syncthreads();

  // partial logsumexp over this block's 32 f values (lanes 0..31 of wave 0)
  if (t < 32) {
    const float fval = red[0][t] + red[1][t] + red[2][t] + red[3][t] + b2[0];
    float mm = fval;
    #pragma unroll
    for (int o = 1; o < 32; o <<= 1) mm = fmaxf(mm, __shfl_xor(mm, o));
    float e = expf(fval - mm);
    #pragma unroll
    for (int o = 1; o < 32; o <<= 1) e += __shfl_xor(e, o);
    if (t == 0) { mpart[blk] = mm; lpart[blk] = e; }
  }
}

// ============ finisher: 128 blocks x 128 thr ============
__global__ __launch_bounds__(128) void Kfin(
    const float* __restrict__ mpart, const float* __restrict__ lpart,
    const float* __restrict__ l2part, const float* __restrict__ bvec,
    const float* __restrict__ w, const float* __restrict__ pxw_part,
    const float* __restrict__ fzw_part, const float* __restrict__ b2,
    float* __restrict__ out) {
  const int b = blockIdx.x, t = threadIdx.x;
  __shared__ float red3[2];
  const int lane = t & 63, wid = t >> 6;
  // pwx finish
  float lg = bvec[t];
  #pragma unroll
  for (int kc = 0; kc < 16; ++kc) lg += l2part[((size_t)b * 16 + kc) * 128 + t];
  float term = w[b * 128 + t] * lg - softplusf(lg);
  #pragma unroll
  for (int o = 1; o < 64; o <<= 1) term += __shfl_xor(term, o);
  if (lane == 0) red3[wid] = term;
  __syncthreads();
  if (t == 0) {
    const float pwx = red3[0] + red3[1];
    // combine 8 logsumexp partials
    float mm = mpart[b];
    #pragma unroll
    for (int q = 1; q < 8; ++q) mm = fmaxf(mm, mpart[q * 128 + b]);
    float l = 0.f;
    #pragma unroll
    for (int q = 0; q < 8; ++q) l += lpart[q * 128 + b] * expf(mpart[q * 128 + b] - mm);
    const float logZ = mm + logf(l) - logf((float)S_) + (float)D_ * logf(2.f);
    float pxw = 0.f;
    #pragma unroll
    for (int ic = 0; ic < 8; ++ic) pxw += pxw_part[(size_t)b * 8 + ic];
    float fzw = b2[0];
    #pragma unroll
    for (int hc = 0; hc < 4; ++hc) fzw += fzw_part[(size_t)b * 4 + hc];
    const float r_wz = fminf(fzw - logZ, 0.f);
    out[b] = -(pxw - pwx + r_wz);
  }
}

extern "C" void kernel_launch(void* const* d_in, const int* in_sizes, int n_in,
                              void* d_out, int out_size, void* d_ws, size_t ws_size,
                              hipStream_t stream) {
  const float* x    = (const float*)d_in[0];
  // d_in[1] = y, unused
  const float* w    = (const float*)d_in[2];
  const float* z    = (const float*)d_in[3];
  const float* wt   = (const float*)d_in[4];
  const float* W    = (const float*)d_in[5];
  const float* bvec = (const float*)d_in[6];
  const float* cvec = (const float*)d_in[7];
  const float* W1   = (const float*)d_in[8];
  const float* b1   = (const float*)d_in[9];
  const float* W2   = (const float*)d_in[10];
  const float* b2   = (const float*)d_in[11];

  float* ws_f = (float*)d_ws;
  unsigned short* Bp    = (unsigned short*)ws_f;              // 65536 us = 32768 f
  float* zb1            = ws_f + 32768;                       // 65536 f
  float* l2part         = ws_f + 98304;                       // 262144 f
  float* pxw_part       = ws_f + 360448;                      // 1024 f
  float* fzw_part       = ws_f + 361472;                      // 512 f
  float* mpart          = ws_f + 361984;                      // 1024 f
  float* lpart          = ws_f + 363008;                      // 1024 f
  float* out = (float*)d_out;

  hipLaunchKernelGGL(Kprep3, dim3(2208), dim3(256), 0, stream,
                     x, w, z, W, cvec, W1, b1, W2, Bp, l2part, zb1, pxw_part, fzw_part);
  hipLaunchKernelGGL(Kmfma, dim3(1024), dim3(256), 0, stream,
                     wt, Bp, zb1, W2, b2, mpart, lpart);
  hipLaunchKernelGGL(Kfin, dim3(B_), dim3(128), 0, stream,
                     mpart, lpart, l2part, bvec, w, pxw_part, fzw_part, b2, out);
}